// Round 9
// baseline (228.854 us; speedup 1.0000x reference)
//
#include <hip/hip_runtime.h>

#define DIM   1024
#define BATCH 128
#define MAT   (BATCH*DIM)     // 131072
#define NROWS MAT
#define DS    32

typedef float f4n __attribute__((ext_vector_type(4)));

// D3 writes rows with (row&31)<15. Remaining 17/32 handled by j-index space:
// row(j) = (j/17)*32 + 15 + (j%17),  j in [0, 69632).
#define JCAP1 25088   // layer1 writers: 3584 waves x 7
#define JCAP2 50176   // layer2: +3584 x 7
#define JCAP3 69632   // layer3: 3584 x 6 (capped)

struct Params {
  const float *x,*Wq,*bq,*Wk,*bk,*Wv,*bv,*Wo,*bo,*W1,*b1,*W2,*b2;
  float *out,*nw;
  float *q,*k,*v,*araw,*x2,*h,*rinv,*P;
};

// ---------------------------------------------------------------------------
// rinv-based nw-row writer (reduction-free; bit-identical to fused path).
// k row from L2; rinv/q wave-uniform loads.
// ---------------------------------------------------------------------------
__device__ __forceinline__ void write_row(const Params& p, int row, int lane)
{
  const int b = row >> 10;
  const float4* __restrict__ k4 = (const float4*)(p.k + ((size_t)b<<10));
  const float4 k0 = k4[lane      ], k1 = k4[lane +  64];
  const float4 k2 = k4[lane + 128], k3 = k4[lane + 192];
  const float c = p.q[row] * 0.03125f;
  const float rinv = p.rinv[row];
  f4n* o = (f4n*)(p.nw + ((size_t)row<<10));
  f4n s0, s1, s2, s3;
  s0.x=__expf(c*k0.x)*rinv; s0.y=__expf(c*k0.y)*rinv;
  s0.z=__expf(c*k0.z)*rinv; s0.w=__expf(c*k0.w)*rinv;
  s1.x=__expf(c*k1.x)*rinv; s1.y=__expf(c*k1.y)*rinv;
  s1.z=__expf(c*k1.z)*rinv; s1.w=__expf(c*k1.w)*rinv;
  s2.x=__expf(c*k2.x)*rinv; s2.y=__expf(c*k2.y)*rinv;
  s2.z=__expf(c*k2.z)*rinv; s2.w=__expf(c*k2.w)*rinv;
  s3.x=__expf(c*k3.x)*rinv; s3.y=__expf(c*k3.y)*rinv;
  s3.z=__expf(c*k3.z)*rinv; s3.w=__expf(c*k3.w)*rinv;
  __builtin_nontemporal_store(s0, &o[lane      ]);
  __builtin_nontemporal_store(s1, &o[lane +  64]);
  __builtin_nontemporal_store(s2, &o[lane + 128]);
  __builtin_nontemporal_store(s3, &o[lane + 192]);
}

// ---------------------------------------------------------------------------
// Split-K partial GEMM tile (proven): tile 128b x 64n, KC steps of 32.
// ---------------------------------------------------------------------------
__device__ __forceinline__ void gemm_tile(
    const float* __restrict__ X, const float* __restrict__ W,
    float* __restrict__ Pout, int n0, int k0, int KC,
    float* xt, float* wt)
{
  const int tid = threadIdx.x;
  const int tn = tid & 15, tb = tid >> 4;
  const int b_base = tb*8, n_base = tn*4;
  float acc[8][4];
#pragma unroll
  for (int i=0;i<8;++i)
#pragma unroll
    for (int j=0;j<4;++j) acc[i][j]=0.f;

  for (int s=0; s<KC/DS; ++s) {
    const int kk = k0 + s*DS;
#pragma unroll
    for (int r=0;r<4;++r) {
      const int row = (tid>>3) + 32*r;
      const int c0  = (tid&7)*4;
      const float4 vv = *(const float4*)(X + (size_t)row*DIM + kk + c0);
      xt[(c0+0)*132+row]=vv.x; xt[(c0+1)*132+row]=vv.y;
      xt[(c0+2)*132+row]=vv.z; xt[(c0+3)*132+row]=vv.w;
    }
#pragma unroll
    for (int r=0;r<2;++r) {
      const int row = (tid>>3) + 32*r;
      const int c0  = (tid&7)*4;
      const f4n vv = __builtin_nontemporal_load(
          (const f4n*)(W + (size_t)(n0+row)*DIM + kk + c0));
      wt[(c0+0)*68+row]=vv.x; wt[(c0+1)*68+row]=vv.y;
      wt[(c0+2)*68+row]=vv.z; wt[(c0+3)*68+row]=vv.w;
    }
    __syncthreads();
#pragma unroll 4
    for (int d=0; d<DS; ++d) {
      const float4 xa0 = *(const float4*)&xt[d*132 + b_base];
      const float4 xa1 = *(const float4*)&xt[d*132 + b_base + 4];
      const float4 wa  = *(const float4*)&wt[d*68  + n_base];
      const float xr[8] = {xa0.x,xa0.y,xa0.z,xa0.w, xa1.x,xa1.y,xa1.z,xa1.w};
      const float wr[4] = {wa.x,wa.y,wa.z,wa.w};
#pragma unroll
      for (int bb=0;bb<8;++bb)
#pragma unroll
        for (int nn=0;nn<4;++nn) acc[bb][nn] += xr[bb]*wr[nn];
    }
    __syncthreads();
  }
#pragma unroll
  for (int bb=0;bb<8;++bb) {
    const float4 st = make_float4(acc[bb][0],acc[bb][1],acc[bb][2],acc[bb][3]);
    *(float4*)(Pout + (size_t)(b_base+bb)*DIM + n0 + n_base) = st;
  }
}

__global__ __launch_bounds__(256) void qkv_partial(
    const float* __restrict__ X, const float* __restrict__ W0,
    const float* __restrict__ W1, const float* __restrict__ W2,
    float* __restrict__ P)
{
  __shared__ float xt[DS*132];
  __shared__ float wt[DS*68];
  const int z = blockIdx.z;
  const float* W = (z==0)?W0:(z==1)?W1:W2;
  gemm_tile(X, W, P + (size_t)(z*8+blockIdx.y)*MAT,
            blockIdx.x*64, blockIdx.y*128, 128, xt, wt);
}

__global__ __launch_bounds__(256) void qkv_reduce(Params p)
{
  const int t = blockIdx.x*256 + threadIdx.x;     // 0..98303
  const int z = t >> 15, idx4 = t & 32767;
  const float4* Pz = (const float4*)(p.P + (size_t)z*8*MAT);
  const float*  bias = (z==0) ? p.bq : (z==1) ? p.bk : p.bv;
  float* outz = (z==0) ? p.q : (z==1) ? p.k : p.v;
  float4 s = Pz[idx4];
#pragma unroll
  for (int sp=1; sp<8; ++sp) {
    const float4 t2 = Pz[sp*(MAT/4)+idx4];
    s.x+=t2.x; s.y+=t2.y; s.z+=t2.z; s.w+=t2.w;
  }
  const float4 b4 = ((const float4*)bias)[idx4 & 255];
  s.x+=b4.x; s.y+=b4.y; s.z+=b4.z; s.w+=b4.w;
  ((float4*)outz)[idx4] = s;
}

// ---------------------------------------------------------------------------
// attn_all: 1024 blocks x 4 waves; wave gw owns rows [gw*32, gw*32+32) — all
// in one batch (32 waves/batch), so k,v are register-cached ONCE per wave.
// Per row: exps once, shfl reduce -> araw+rinv (all rows), write nw for the
// first 15 rows of the 32 (uniform work per wave, no tail skew).
// ---------------------------------------------------------------------------
__global__ __launch_bounds__(256,4) void attn_all(Params p)
{
  const int gw = blockIdx.x*4 + (threadIdx.x>>6);  // 0..4095
  const int lane = threadIdx.x & 63;
  const int b = gw >> 5;
  const float4* __restrict__ k4 = (const float4*)(p.k + ((size_t)b<<10));
  const float4* __restrict__ v4 = (const float4*)(p.v + ((size_t)b<<10));
  float4 kr[4], vr[4];
#pragma unroll
  for (int t=0;t<4;++t) { kr[t] = k4[lane + 64*t]; vr[t] = v4[lane + 64*t]; }
  const int r0 = gw*32;
#pragma unroll 1
  for (int r=0;r<32;++r) {
    const int row = r0 + r;
    const float c = p.q[row] * 0.03125f;
    float e[16];
#pragma unroll
    for (int t=0;t<4;++t) {
      e[4*t+0]=__expf(c*kr[t].x); e[4*t+1]=__expf(c*kr[t].y);
      e[4*t+2]=__expf(c*kr[t].z); e[4*t+3]=__expf(c*kr[t].w);
    }
    float sum=0.f, dot=0.f;
#pragma unroll
    for (int t=0;t<4;++t) {
      sum += (e[4*t]+e[4*t+1])+(e[4*t+2]+e[4*t+3]);
      dot += e[4*t]*vr[t].x + e[4*t+1]*vr[t].y + e[4*t+2]*vr[t].z + e[4*t+3]*vr[t].w;
    }
#pragma unroll
    for (int off=32; off>=1; off>>=1) {
      sum += __shfl_xor(sum, off);
      dot += __shfl_xor(dot, off);
    }
    const float rinv = 1.f/sum;
    if (r < 15) {
      f4n* o = (f4n*)(p.nw + ((size_t)row<<10));
#pragma unroll
      for (int t=0;t<4;++t) {
        f4n st;
        st.x=e[4*t]*rinv; st.y=e[4*t+1]*rinv;
        st.z=e[4*t+2]*rinv; st.w=e[4*t+3]*rinv;
        __builtin_nontemporal_store(st, &o[lane + 64*t]);
      }
    }
    if (lane==0) { p.araw[row] = dot*rinv; p.rinv[row] = rinv; }
  }
}

// ---------------------------------------------------------------------------
// fused_layer: blocks 0..127 = deep-K GEMM (no split-K, no reduce dispatch):
// out[:, g*8 .. g*8+8) = [relu](X @ W^T + bias) [+ extra], K=1024 in 16
// chunks of 64 staged in LDS (37 KB -> 4 blocks/CU). Blocks 128..1023 =
// nw writers over the j-index space (rinv-based).
// ---------------------------------------------------------------------------
__global__ __launch_bounds__(256,4) void fused_layer(Params p,
    const float* __restrict__ X, const float* __restrict__ W,
    const float* __restrict__ bias, const float* __restrict__ extra,
    float* __restrict__ out, int relu, int jbase, int jcap, int perw)
{
  __shared__ float xt[64*132];   // [k][b], padded
  __shared__ float wt[64*12];    // [k][n], padded
  const int bid = blockIdx.x, tid = threadIdx.x;
  const int wave = tid>>6, lane = tid&63;

  if (bid >= 128) {
    const int w = (bid-128)*4 + wave;      // 0..3583
    int j = jbase + w*perw;
#pragma unroll 1
    for (int i=0;i<perw;++i,++j) {
      if (j >= jcap) break;
      const int q17 = j/17, r17 = j - q17*17;
      write_row(p, q17*32 + 15 + r17, lane);
    }
    return;
  }

  const int n0 = bid*8;
  const int tb = tid & 31, tn = tid >> 5;    // b-group (4 rows), n (1 col)
  const int b0 = tb*4;
  float acc[4] = {0.f,0.f,0.f,0.f};

  for (int kc=0; kc<DIM; kc+=64) {
    // stage X[128b x 64k] transposed -> xt[k][b]
    {
      const int c0 = (tid&15)*4;             // k-offset 0..60
      const int rb = tid>>4;                 // 0..15
#pragma unroll
      for (int rr=0;rr<8;++rr) {
        const int bb = rb + 16*rr;
        const float4 vv = *(const float4*)(X + (size_t)bb*DIM + kc + c0);
        xt[(c0+0)*132+bb]=vv.x; xt[(c0+1)*132+bb]=vv.y;
        xt[(c0+2)*132+bb]=vv.z; xt[(c0+3)*132+bb]=vv.w;
      }
    }
    // stage W[8n x 64k] transposed -> wt[k][n]
    {
      const int nn = tid>>5;                 // 0..7
      const int c0 = (tid&31)*2;             // k-offset 0..62
      const float2 vv = *(const float2*)(W + (size_t)(n0+nn)*DIM + kc + c0);
      wt[(c0+0)*12+nn]=vv.x; wt[(c0+1)*12+nn]=vv.y;
    }
    __syncthreads();
#pragma unroll 8
    for (int k=0;k<64;++k) {
      const float4 x4 = *(const float4*)&xt[k*132 + b0];
      const float  wv = wt[k*12 + tn];
      acc[0] += x4.x*wv; acc[1] += x4.y*wv;
      acc[2] += x4.z*wv; acc[3] += x4.w*wv;
    }
    __syncthreads();
  }

  const int col = n0 + tn;
  const float bv = bias[col];
#pragma unroll
  for (int j=0;j<4;++j) {
    const int bb = b0 + j;
    float s = acc[j] + bv;
    if (relu) s = fmaxf(s, 0.f);
    if (extra) s += extra[(size_t)bb*DIM + col];
    out[(size_t)bb*DIM + col] = s;
  }
}

// ---------------------------------------------------------------------------
extern "C" void kernel_launch(void* const* d_in, const int* in_sizes, int n_in,
                              void* d_out, int out_size, void* d_ws, size_t ws_size,
                              hipStream_t stream)
{
  (void)in_sizes; (void)n_in; (void)out_size; (void)ws_size;
  Params p;
  p.x  = (const float*)d_in[0];
  p.Wq = (const float*)d_in[1];  p.bq = (const float*)d_in[2];
  p.Wk = (const float*)d_in[3];  p.bk = (const float*)d_in[4];
  p.Wv = (const float*)d_in[5];  p.bv = (const float*)d_in[6];
  p.Wo = (const float*)d_in[7];  p.bo = (const float*)d_in[8];
  p.W1 = (const float*)d_in[9];  p.b1 = (const float*)d_in[10];
  p.W2 = (const float*)d_in[11]; p.b2 = (const float*)d_in[12];
  p.out = (float*)d_out;
  p.nw  = p.out + MAT;
  float* ws = (float*)d_ws;
  p.q    = ws;         p.k    = ws + MAT;   p.v = ws + 2*MAT;
  p.araw = ws + 3*MAT; p.x2   = ws + 4*MAT; p.h = ws + 5*MAT;
  p.rinv = ws + 6*MAT; p.P    = ws + 7*MAT;   // P: 24*MAT floats

  qkv_partial<<<dim3(16,8,3), 256, 0, stream>>>(p.x, p.Wq, p.Wk, p.Wv, p.P);
  qkv_reduce<<<384, 256, 0, stream>>>(p);

  attn_all<<<1024, 256, 0, stream>>>(p);

  fused_layer<<<1024, 256, 0, stream>>>(p, p.araw, p.Wo, p.bo, p.x,
                                        p.x2, 0, 0,     JCAP1, 7);
  fused_layer<<<1024, 256, 0, stream>>>(p, p.x2,  p.W1, p.b1, nullptr,
                                        p.h,  1, JCAP1, JCAP2, 7);
  fused_layer<<<1024, 256, 0, stream>>>(p, p.h,   p.W2, p.b2, p.x2,
                                        p.out, 0, JCAP2, JCAP3, 6);
}

// Round 10
// 227.562 us; speedup vs baseline: 1.0057x; 1.0057x over previous
//
#include <hip/hip_runtime.h>

#define DIM   1024
#define BATCH 128
#define MAT   (BATCH*DIM)     // 131072
#define NROWS MAT
#define DS    32

typedef float f4n __attribute__((ext_vector_type(4)));

// Row regions (cumulative, exact, no atomics). Writers get consecutive
// chunks (k-register reuse; chunk rarely crosses a batch boundary).
#define QAT_END 18432   // attn: 3072 waves x 6
#define A1_END  46080   // chainA1: 3072 x 9
#define B1_END  53248   // chainB1: 3584 x 2
#define A2_END  80896   // chainA2: 3072 x 9
#define B2_END  88064   // chainB2: 3584 x 2
#define A3_END  115712  // chainA3: 3072 x 9
                        // chainB3: remaining 15360 (1024 x 5 + 2560 x 4)

struct Params {
  const float *x,*Wq,*bq,*Wk,*bk,*Wv,*bv,*Wo,*bo,*W1,*b1,*W2,*b2;
  float *out,*nw;
  float *q,*k,*v,*araw,*x2,*h,*rinv,*P;
};

// ---------------------------------------------------------------------------
// Consecutive-chunk nw writer. k row register-cached, reloaded on batch
// change. USE_RINV: rinv precomputed by AR (reduction-free). !USE_RINV:
// local shfl reduction (attn dispatch; rinv for these rows may not be
// written yet). nt stores: write-once stream, keep L2 for k/W.
// ---------------------------------------------------------------------------
template<bool USE_RINV>
__device__ __forceinline__ void write_chunk(const Params& p, int r0, int r1, int lane)
{
  int bcur = -1;
  float4 kr[4];
#pragma unroll 1
  for (int row = r0; row < r1; ++row) {
    const int b = row >> 10;
    if (b != bcur) {
      bcur = b;
      const float4* __restrict__ k4 = (const float4*)(p.k + ((size_t)b<<10));
#pragma unroll
      for (int t=0;t<4;++t) kr[t] = k4[lane + 64*t];
    }
    const float c = p.q[row] * 0.03125f;
    float e[16];
#pragma unroll
    for (int t=0;t<4;++t) {
      e[4*t+0]=__expf(c*kr[t].x); e[4*t+1]=__expf(c*kr[t].y);
      e[4*t+2]=__expf(c*kr[t].z); e[4*t+3]=__expf(c*kr[t].w);
    }
    float rinv;
    if (USE_RINV) {
      rinv = p.rinv[row];
    } else {
      float sum = 0.f;
#pragma unroll
      for (int i=0;i<16;++i) sum += e[i];
#pragma unroll
      for (int off=32; off>=1; off>>=1) sum += __shfl_xor(sum, off);
      rinv = 1.f/sum;
    }
    f4n* o = (f4n*)(p.nw + ((size_t)row<<10));
#pragma unroll
    for (int t=0;t<4;++t) {
      f4n st;
      st.x=e[4*t]*rinv;   st.y=e[4*t+1]*rinv;
      st.z=e[4*t+2]*rinv; st.w=e[4*t+3]*rinv;
      __builtin_nontemporal_store(st, &o[lane + 64*t]);
    }
  }
}

// ---------------------------------------------------------------------------
// Split-K partial GEMM tile (proven): tile 128b x 64n, KC steps of 32.
// ---------------------------------------------------------------------------
__device__ __forceinline__ void gemm_tile(
    const float* __restrict__ X, const float* __restrict__ W,
    float* __restrict__ Pout, int n0, int k0, int KC,
    float* xt, float* wt)
{
  const int tid = threadIdx.x;
  const int tn = tid & 15, tb = tid >> 4;
  const int b_base = tb*8, n_base = tn*4;
  float acc[8][4];
#pragma unroll
  for (int i=0;i<8;++i)
#pragma unroll
    for (int j=0;j<4;++j) acc[i][j]=0.f;

  for (int s=0; s<KC/DS; ++s) {
    const int kk = k0 + s*DS;
#pragma unroll
    for (int r=0;r<4;++r) {
      const int row = (tid>>3) + 32*r;
      const int c0  = (tid&7)*4;
      const float4 vv = *(const float4*)(X + (size_t)row*DIM + kk + c0);
      xt[(c0+0)*132+row]=vv.x; xt[(c0+1)*132+row]=vv.y;
      xt[(c0+2)*132+row]=vv.z; xt[(c0+3)*132+row]=vv.w;
    }
#pragma unroll
    for (int r=0;r<2;++r) {
      const int row = (tid>>3) + 32*r;
      const int c0  = (tid&7)*4;
      const f4n vv = __builtin_nontemporal_load(
          (const f4n*)(W + (size_t)(n0+row)*DIM + kk + c0));
      wt[(c0+0)*68+row]=vv.x; wt[(c0+1)*68+row]=vv.y;
      wt[(c0+2)*68+row]=vv.z; wt[(c0+3)*68+row]=vv.w;
    }
    __syncthreads();
#pragma unroll 4
    for (int d=0; d<DS; ++d) {
      const float4 xa0 = *(const float4*)&xt[d*132 + b_base];
      const float4 xa1 = *(const float4*)&xt[d*132 + b_base + 4];
      const float4 wa  = *(const float4*)&wt[d*68  + n_base];
      const float xr[8] = {xa0.x,xa0.y,xa0.z,xa0.w, xa1.x,xa1.y,xa1.z,xa1.w};
      const float wr[4] = {wa.x,wa.y,wa.z,wa.w};
#pragma unroll
      for (int bb=0;bb<8;++bb)
#pragma unroll
        for (int nn=0;nn<4;++nn) acc[bb][nn] += xr[bb]*wr[nn];
    }
    __syncthreads();
  }
#pragma unroll
  for (int bb=0;bb<8;++bb) {
    const float4 st = make_float4(acc[bb][0],acc[bb][1],acc[bb][2],acc[bb][3]);
    *(float4*)(Pout + (size_t)(b_base+bb)*DIM + n0 + n_base) = st;
  }
}

__global__ __launch_bounds__(256) void qkv_partial(
    const float* __restrict__ X, const float* __restrict__ W0,
    const float* __restrict__ W1, const float* __restrict__ W2,
    float* __restrict__ P)
{
  __shared__ float xt[DS*132];
  __shared__ float wt[DS*68];
  const int z = blockIdx.z;
  const float* W = (z==0)?W0:(z==1)?W1:W2;
  gemm_tile(X, W, P + (size_t)(z*8+blockIdx.y)*MAT,
            blockIdx.x*64, blockIdx.y*128, 128, xt, wt);
}

__global__ __launch_bounds__(256) void qkv_reduce(Params p)
{
  const int t = blockIdx.x*256 + threadIdx.x;     // 0..98303
  const int z = t >> 15, idx4 = t & 32767;
  const float4* Pz = (const float4*)(p.P + (size_t)z*8*MAT);
  const float*  bias = (z==0) ? p.bq : (z==1) ? p.bk : p.bv;
  float* outz = (z==0) ? p.q : (z==1) ? p.k : p.v;
  float4 s = Pz[idx4];
#pragma unroll
  for (int sp=1; sp<8; ++sp) {
    const float4 t2 = Pz[sp*(MAT/4)+idx4];
    s.x+=t2.x; s.y+=t2.y; s.z+=t2.z; s.w+=t2.w;
  }
  const float4 b4 = ((const float4*)bias)[idx4 & 255];
  s.x+=b4.x; s.y+=b4.y; s.z+=b4.z; s.w+=b4.w;
  ((float4*)outz)[idx4] = s;
}

// ---------------------------------------------------------------------------
// attn: blocks 0..255 = AR (1024 waves x 128 consecutive rows, one batch per
// wave -> k,v cached once): araw + rinv for ALL rows, VALU-bound ~13 us.
// blocks 256..1023 = writers (3072 waves x 6 rows, local-sum) ~75 MB.
// ---------------------------------------------------------------------------
__global__ __launch_bounds__(256,4) void attn_mixed(Params p)
{
  const int bid = blockIdx.x, tid = threadIdx.x;
  const int wave = tid>>6, lane = tid&63;
  if (bid < 256) {
    const int gw = bid*4 + wave;          // 0..1023
    const int b = gw >> 3;                // 8 waves per batch
    const float4* __restrict__ k4 = (const float4*)(p.k + ((size_t)b<<10));
    const float4* __restrict__ v4 = (const float4*)(p.v + ((size_t)b<<10));
    float4 kr[4], vr[4];
#pragma unroll
    for (int t=0;t<4;++t) { kr[t] = k4[lane + 64*t]; vr[t] = v4[lane + 64*t]; }
    const int r0 = gw*128;
#pragma unroll 1
    for (int r=0;r<128;++r) {
      const int row = r0 + r;
      const float c = p.q[row] * 0.03125f;
      float sum=0.f, dot=0.f;
#pragma unroll
      for (int t=0;t<4;++t) {
        const float ex=__expf(c*kr[t].x), ey=__expf(c*kr[t].y);
        const float ez=__expf(c*kr[t].z), ew=__expf(c*kr[t].w);
        sum += (ex+ey)+(ez+ew);
        dot += ex*vr[t].x + ey*vr[t].y + ez*vr[t].z + ew*vr[t].w;
      }
#pragma unroll
      for (int off=32; off>=1; off>>=1) {
        sum += __shfl_xor(sum, off);
        dot += __shfl_xor(dot, off);
      }
      const float rinv = 1.f/sum;
      if (lane==0) { p.araw[row] = dot*rinv; p.rinv[row] = rinv; }
    }
  } else {
    const int w = (bid-256)*4 + wave;     // 0..3071
    write_chunk<false>(p, w*6, w*6 + 6, lane);
  }
}

// ---------------------------------------------------------------------------
// chainA: blocks 0..255 = split-16 GEMM partials (K=64); 256..1023 = writers
// (3072 waves x 9 rows, rinv). chainB: 0..127 = reduce+epilogue; 128..1023 =
// writers (3584 waves x 2 rows, rinv; B3 variant covers the tail).
// ---------------------------------------------------------------------------
__global__ __launch_bounds__(256,4) void chainA(Params p,
    const float* __restrict__ X, const float* __restrict__ W, int wbase)
{
  __shared__ float xt[DS*132];
  __shared__ float wt[DS*68];
  const int bid = blockIdx.x, tid = threadIdx.x;
  const int wave = tid>>6, lane = tid&63;
  if (bid < 256) {
    gemm_tile(X, W, p.P + (size_t)(bid&15)*MAT, (bid>>4)*64, (bid&15)*64, 64, xt, wt);
  } else {
    const int w = (bid-256)*4 + wave;     // 0..3071
    const int r0 = wbase + w*9;
    write_chunk<true>(p, r0, r0 + 9, lane);
  }
}

__global__ __launch_bounds__(256,4) void chainB(Params p,
    const float* __restrict__ bias, const float* __restrict__ extra,
    float* __restrict__ out, int relu, int wbase, int last)
{
  const int bid = blockIdx.x, tid = threadIdx.x;
  const int wave = tid>>6, lane = tid&63;
  if (bid < 128) {
    const int idx4 = bid*256 + tid;
    const float4* P4 = (const float4*)p.P;
    float4 s = P4[idx4];
#pragma unroll
    for (int sp=1; sp<16; ++sp) {
      const float4 t2 = P4[sp*(MAT/4)+idx4];
      s.x+=t2.x; s.y+=t2.y; s.z+=t2.z; s.w+=t2.w;
    }
    const float4 b4 = ((const float4*)bias)[idx4 & 255];
    s.x+=b4.x; s.y+=b4.y; s.z+=b4.z; s.w+=b4.w;
    if (relu) { s.x=fmaxf(s.x,0.f); s.y=fmaxf(s.y,0.f);
                s.z=fmaxf(s.z,0.f); s.w=fmaxf(s.w,0.f); }
    if (extra) {
      const float4 e = ((const float4*)extra)[idx4];
      s.x+=e.x; s.y+=e.y; s.z+=e.z; s.w+=e.w;
    }
    ((float4*)out)[idx4] = s;
  } else {
    const int w = (bid-128)*4 + wave;     // 0..3583
    if (!last) {
      const int r0 = wbase + w*2;
      write_chunk<true>(p, r0, r0 + 2, lane);
    } else {
      // tail: 15360 rows = 1024 waves x 5 + 2560 waves x 4
      int r0, n;
      if (w < 1024) { r0 = wbase + w*5;            n = 5; }
      else          { r0 = wbase + 5120 + (w-1024)*4; n = 4; }
      write_chunk<true>(p, r0, r0 + n, lane);
    }
  }
}

// ---------------------------------------------------------------------------
extern "C" void kernel_launch(void* const* d_in, const int* in_sizes, int n_in,
                              void* d_out, int out_size, void* d_ws, size_t ws_size,
                              hipStream_t stream)
{
  (void)in_sizes; (void)n_in; (void)out_size; (void)ws_size;
  Params p;
  p.x  = (const float*)d_in[0];
  p.Wq = (const float*)d_in[1];  p.bq = (const float*)d_in[2];
  p.Wk = (const float*)d_in[3];  p.bk = (const float*)d_in[4];
  p.Wv = (const float*)d_in[5];  p.bv = (const float*)d_in[6];
  p.Wo = (const float*)d_in[7];  p.bo = (const float*)d_in[8];
  p.W1 = (const float*)d_in[9];  p.b1 = (const float*)d_in[10];
  p.W2 = (const float*)d_in[11]; p.b2 = (const float*)d_in[12];
  p.out = (float*)d_out;
  p.nw  = p.out + MAT;
  float* ws = (float*)d_ws;
  p.q    = ws;         p.k    = ws + MAT;   p.v = ws + 2*MAT;
  p.araw = ws + 3*MAT; p.x2   = ws + 4*MAT; p.h = ws + 5*MAT;
  p.rinv = ws + 6*MAT; p.P    = ws + 7*MAT;   // P: 24*MAT floats

  qkv_partial<<<dim3(16,8,3), 256, 0, stream>>>(p.x, p.Wq, p.Wk, p.Wv, p.P);
  qkv_reduce<<<384, 256, 0, stream>>>(p);

  attn_mixed<<<1024, 256, 0, stream>>>(p);

  chainA<<<1024, 256, 0, stream>>>(p, p.araw, p.Wo, QAT_END);
  chainB<<<1024, 256, 0, stream>>>(p, p.bo, p.x, p.x2, 0, A1_END, 0);

  chainA<<<1024, 256, 0, stream>>>(p, p.x2, p.W1, B1_END);
  chainB<<<1024, 256, 0, stream>>>(p, p.b1, nullptr, p.h, 1, A2_END, 0);

  chainA<<<1024, 256, 0, stream>>>(p, p.h, p.W2, B2_END);
  chainB<<<1024, 256, 0, stream>>>(p, p.b2, p.x2, p.out, 0, A3_END, 1);
}

// Round 11
// 207.502 us; speedup vs baseline: 1.1029x; 1.0967x over previous
//
#include <hip/hip_runtime.h>

#define DIM   1024
#define BATCH 128
#define MAT   (BATCH*DIM)     // 131072
#define NROWS MAT
#define DS    32

typedef float f4n __attribute__((ext_vector_type(4)));

// contiguous nw-row regions per dispatch (rows, cumulative; sum = 131072)
#define A1_R0 0
#define A1_N  26624
#define B1_R0 26624
#define B1_N  17408
#define A2_R0 44032
#define A2_N  26624
#define B2_R0 70656
#define B2_N  17408
#define A3_R0 88064
#define A3_N  26624
#define B3_R0 114688
#define B3_N  16384

struct Params {
  const float *x,*Wq,*bq,*Wk,*bk,*Wv,*bv,*Wo,*bo,*W1,*b1,*W2,*b2;
  float *out,*nw;
  float *q,*k,*v,*araw,*x2,*h,*rinv,*P;
};

// ---------------------------------------------------------------------------
// Fill-mimic nw writer: thread T of NT writer-threads writes flat-f4 indices
// base+T, base+T+NT, ... — one PLAIN dwordx4 store per iteration, exactly the
// poison-fill's addressing (contiguous chip-wide front, block-stride). A wave
// covers 1KB of one row (256 f4/row, wave=64 lanes); q/rinv wave-uniform;
// k segment is a coalesced 1KB L2 hit. rinv precomputed -> no cross-lane ops.
// ---------------------------------------------------------------------------
__device__ __forceinline__ void fill_write(const Params& p, int T, int NT,
                                           int row0, int nrows)
{
  const size_t base = (size_t)row0 << 8;        // f4 index (256 f4 per row)
  const size_t end  = base + ((size_t)nrows << 8);
  f4n* __restrict__ nw4 = (f4n*)p.nw;
#pragma unroll 2
  for (size_t f = base + T; f < end; f += NT) {
    const int row = (int)(f >> 8);
    const int c4  = (int)(f & 255);
    const int b   = row >> 10;
    const f4n kk = *(const f4n*)(p.k + ((size_t)b<<10) + (c4<<2));
    const float c    = p.q[row] * 0.03125f;
    const float rinv = p.rinv[row];
    f4n st;
    st.x=__expf(c*kk.x)*rinv; st.y=__expf(c*kk.y)*rinv;
    st.z=__expf(c*kk.z)*rinv; st.w=__expf(c*kk.w)*rinv;
    nw4[f] = st;                                 // plain store, through L2
  }
}

// ---------------------------------------------------------------------------
// Split-K partial GEMM tile (proven): tile 128b x 64n, KC steps of 32.
// ---------------------------------------------------------------------------
__device__ __forceinline__ void gemm_tile(
    const float* __restrict__ X, const float* __restrict__ W,
    float* __restrict__ Pout, int n0, int k0, int KC,
    float* xt, float* wt)
{
  const int tid = threadIdx.x;
  const int tn = tid & 15, tb = tid >> 4;
  const int b_base = tb*8, n_base = tn*4;
  float acc[8][4];
#pragma unroll
  for (int i=0;i<8;++i)
#pragma unroll
    for (int j=0;j<4;++j) acc[i][j]=0.f;

  for (int s=0; s<KC/DS; ++s) {
    const int kk = k0 + s*DS;
#pragma unroll
    for (int r=0;r<4;++r) {
      const int row = (tid>>3) + 32*r;
      const int c0  = (tid&7)*4;
      const float4 vv = *(const float4*)(X + (size_t)row*DIM + kk + c0);
      xt[(c0+0)*132+row]=vv.x; xt[(c0+1)*132+row]=vv.y;
      xt[(c0+2)*132+row]=vv.z; xt[(c0+3)*132+row]=vv.w;
    }
#pragma unroll
    for (int r=0;r<2;++r) {
      const int row = (tid>>3) + 32*r;
      const int c0  = (tid&7)*4;
      const f4n vv = __builtin_nontemporal_load(
          (const f4n*)(W + (size_t)(n0+row)*DIM + kk + c0));
      wt[(c0+0)*68+row]=vv.x; wt[(c0+1)*68+row]=vv.y;
      wt[(c0+2)*68+row]=vv.z; wt[(c0+3)*68+row]=vv.w;
    }
    __syncthreads();
#pragma unroll 4
    for (int d=0; d<DS; ++d) {
      const float4 xa0 = *(const float4*)&xt[d*132 + b_base];
      const float4 xa1 = *(const float4*)&xt[d*132 + b_base + 4];
      const float4 wa  = *(const float4*)&wt[d*68  + n_base];
      const float xr[8] = {xa0.x,xa0.y,xa0.z,xa0.w, xa1.x,xa1.y,xa1.z,xa1.w};
      const float wr[4] = {wa.x,wa.y,wa.z,wa.w};
#pragma unroll
      for (int bb=0;bb<8;++bb)
#pragma unroll
        for (int nn=0;nn<4;++nn) acc[bb][nn] += xr[bb]*wr[nn];
    }
    __syncthreads();
  }
#pragma unroll
  for (int bb=0;bb<8;++bb) {
    const float4 st = make_float4(acc[bb][0],acc[bb][1],acc[bb][2],acc[bb][3]);
    *(float4*)(Pout + (size_t)(b_base+bb)*DIM + n0 + n_base) = st;
  }
}

__global__ __launch_bounds__(256) void qkv_partial(
    const float* __restrict__ X, const float* __restrict__ W0,
    const float* __restrict__ W1, const float* __restrict__ W2,
    float* __restrict__ P)
{
  __shared__ float xt[DS*132];
  __shared__ float wt[DS*68];
  const int z = blockIdx.z;
  const float* W = (z==0)?W0:(z==1)?W1:W2;
  gemm_tile(X, W, P + (size_t)(z*8+blockIdx.y)*MAT,
            blockIdx.x*64, blockIdx.y*128, 128, xt, wt);
}

__global__ __launch_bounds__(256) void qkv_reduce(Params p)
{
  const int t = blockIdx.x*256 + threadIdx.x;     // 0..98303
  const int z = t >> 15, idx4 = t & 32767;
  const float4* Pz = (const float4*)(p.P + (size_t)z*8*MAT);
  const float*  bias = (z==0) ? p.bq : (z==1) ? p.bk : p.bv;
  float* outz = (z==0) ? p.q : (z==1) ? p.k : p.v;
  float4 s = Pz[idx4];
#pragma unroll
  for (int sp=1; sp<8; ++sp) {
    const float4 t2 = Pz[sp*(MAT/4)+idx4];
    s.x+=t2.x; s.y+=t2.y; s.z+=t2.z; s.w+=t2.w;
  }
  const float4 b4 = ((const float4*)bias)[idx4 & 255];
  s.x+=b4.x; s.y+=b4.y; s.z+=b4.z; s.w+=b4.w;
  ((float4*)outz)[idx4] = s;
}

// ---------------------------------------------------------------------------
// AR-only dispatch: 4096 waves x 32 consecutive rows (one batch per wave ->
// k,v register-cached once). Produces araw + rinv for ALL rows. ~8-10 us.
// ---------------------------------------------------------------------------
__global__ __launch_bounds__(256,4) void attn_ar(Params p)
{
  const int gw = blockIdx.x*4 + (threadIdx.x>>6);  // 0..4095
  const int lane = threadIdx.x & 63;
  const int b = gw >> 5;
  const float4* __restrict__ k4 = (const float4*)(p.k + ((size_t)b<<10));
  const float4* __restrict__ v4 = (const float4*)(p.v + ((size_t)b<<10));
  float4 kr[4], vr[4];
#pragma unroll
  for (int t=0;t<4;++t) { kr[t] = k4[lane + 64*t]; vr[t] = v4[lane + 64*t]; }
  const int r0 = gw*32;
#pragma unroll 1
  for (int r=0;r<32;++r) {
    const int row = r0 + r;
    const float c = p.q[row] * 0.03125f;
    float sum=0.f, dot=0.f;
#pragma unroll
    for (int t=0;t<4;++t) {
      const float ex=__expf(c*kr[t].x), ey=__expf(c*kr[t].y);
      const float ez=__expf(c*kr[t].z), ew=__expf(c*kr[t].w);
      sum += (ex+ey)+(ez+ew);
      dot += ex*vr[t].x + ey*vr[t].y + ez*vr[t].z + ew*vr[t].w;
    }
#pragma unroll
    for (int off=32; off>=1; off>>=1) {
      sum += __shfl_xor(sum, off);
      dot += __shfl_xor(dot, off);
    }
    const float rinv = 1.f/sum;
    if (lane==0) { p.araw[row] = dot*rinv; p.rinv[row] = rinv; }
  }
}

// ---------------------------------------------------------------------------
// chainA: blocks 0..255 = split-16 GEMM partials (K=64); blocks 256..1023 =
// fill-mimic writers (196608 threads) over a contiguous row region.
// chainB: blocks 0..127 = reduce 16 partials + epilogue; 128..1023 = writers
// (229376 threads).
// ---------------------------------------------------------------------------
__global__ __launch_bounds__(256,4) void chainA(Params p,
    const float* __restrict__ X, const float* __restrict__ W,
    int row0, int nrows)
{
  __shared__ float xt[DS*132];
  __shared__ float wt[DS*68];
  const int bid = blockIdx.x, tid = threadIdx.x;
  if (bid < 256) {
    gemm_tile(X, W, p.P + (size_t)(bid&15)*MAT, (bid>>4)*64, (bid&15)*64, 64, xt, wt);
  } else {
    fill_write(p, (bid-256)*256 + tid, 768*256, row0, nrows);
  }
}

__global__ __launch_bounds__(256,4) void chainB(Params p,
    const float* __restrict__ bias, const float* __restrict__ extra,
    float* __restrict__ out, int relu, int row0, int nrows)
{
  const int bid = blockIdx.x, tid = threadIdx.x;
  if (bid < 128) {
    const int idx4 = bid*256 + tid;
    const float4* P4 = (const float4*)p.P;
    float4 s = P4[idx4];
#pragma unroll
    for (int sp=1; sp<16; ++sp) {
      const float4 t2 = P4[sp*(MAT/4)+idx4];
      s.x+=t2.x; s.y+=t2.y; s.z+=t2.z; s.w+=t2.w;
    }
    const float4 b4 = ((const float4*)bias)[idx4 & 255];
    s.x+=b4.x; s.y+=b4.y; s.z+=b4.z; s.w+=b4.w;
    if (relu) { s.x=fmaxf(s.x,0.f); s.y=fmaxf(s.y,0.f);
                s.z=fmaxf(s.z,0.f); s.w=fmaxf(s.w,0.f); }
    if (extra) {
      const float4 e = ((const float4*)extra)[idx4];
      s.x+=e.x; s.y+=e.y; s.z+=e.z; s.w+=e.w;
    }
    ((float4*)out)[idx4] = s;
  } else {
    fill_write(p, (bid-128)*256 + tid, 896*256, row0, nrows);
  }
}

// ---------------------------------------------------------------------------
extern "C" void kernel_launch(void* const* d_in, const int* in_sizes, int n_in,
                              void* d_out, int out_size, void* d_ws, size_t ws_size,
                              hipStream_t stream)
{
  (void)in_sizes; (void)n_in; (void)out_size; (void)ws_size;
  Params p;
  p.x  = (const float*)d_in[0];
  p.Wq = (const float*)d_in[1];  p.bq = (const float*)d_in[2];
  p.Wk = (const float*)d_in[3];  p.bk = (const float*)d_in[4];
  p.Wv = (const float*)d_in[5];  p.bv = (const float*)d_in[6];
  p.Wo = (const float*)d_in[7];  p.bo = (const float*)d_in[8];
  p.W1 = (const float*)d_in[9];  p.b1 = (const float*)d_in[10];
  p.W2 = (const float*)d_in[11]; p.b2 = (const float*)d_in[12];
  p.out = (float*)d_out;
  p.nw  = p.out + MAT;
  float* ws = (float*)d_ws;
  p.q    = ws;         p.k    = ws + MAT;   p.v = ws + 2*MAT;
  p.araw = ws + 3*MAT; p.x2   = ws + 4*MAT; p.h = ws + 5*MAT;
  p.rinv = ws + 6*MAT; p.P    = ws + 7*MAT;   // P: 24*MAT floats

  qkv_partial<<<dim3(16,8,3), 256, 0, stream>>>(p.x, p.Wq, p.Wk, p.Wv, p.P);
  qkv_reduce<<<384, 256, 0, stream>>>(p);

  attn_ar<<<1024, 256, 0, stream>>>(p);

  chainA<<<1024, 256, 0, stream>>>(p, p.araw, p.Wo, A1_R0, A1_N);
  chainB<<<1024, 256, 0, stream>>>(p, p.bo, p.x, p.x2, 0, B1_R0, B1_N);

  chainA<<<1024, 256, 0, stream>>>(p, p.x2, p.W1, A2_R0, A2_N);
  chainB<<<1024, 256, 0, stream>>>(p, p.b1, nullptr, p.h, 1, B2_R0, B2_N);

  chainA<<<1024, 256, 0, stream>>>(p, p.h, p.W2, A3_R0, A3_N);
  chainB<<<1024, 256, 0, stream>>>(p, p.b2, p.x2, p.out, 0, B3_R0, B3_N);
}

// Round 12
// 201.553 us; speedup vs baseline: 1.1355x; 1.0295x over previous
//
#include <hip/hip_runtime.h>

#define DIM   1024
#define BATCH 128
#define MAT   (BATCH*DIM)     // 131072
#define NROWS MAT
#define DS    32

typedef float f4n __attribute__((ext_vector_type(4)));

// Contiguous nw-row regions (cumulative, exact, no atomics):
// attn: 1024 waves x 5          -> [0,      5120)
// A1:   3072 waves x 7          -> [5120,   26624)
// B1:   3584 waves x 6          -> [26624,  48128)
// A2:   3072 waves x 7          -> [48128,  69632)
// B2:   3584 waves x 6          -> [69632,  91136)
// A3:   3072 waves x 7          -> [91136,  112640)
// B3:   512x6 + 3072x5 = 18432  -> [112640, 131072)
#define QAT_B  0
#define A1_B   5120
#define B1_B   26624
#define A2_B   48128
#define B2_B   69632
#define A3_B   91136
#define B3_B   112640

struct Params {
  const float *x,*Wq,*bq,*Wk,*bk,*Wv,*bv,*Wo,*bo,*W1,*b1,*W2,*b2;
  float *out,*nw;
  float *q,*k,*v,*araw,*x2,*h,*rinv,*P;
};

// ---------------------------------------------------------------------------
// Consecutive-chunk nw writer (R6-proven). k row register-cached, reloaded on
// batch change. USE_RINV: reduction-free via precomputed rinv. !USE_RINV:
// local shfl reduction (attn dispatch only). nt stores keep L2 for k/W.
// ---------------------------------------------------------------------------
template<bool USE_RINV>
__device__ __forceinline__ void write_chunk(const Params& p, int r0, int r1, int lane)
{
  int bcur = -1;
  float4 kr[4];
#pragma unroll 1
  for (int row = r0; row < r1; ++row) {
    const int b = row >> 10;
    if (b != bcur) {
      bcur = b;
      const float4* __restrict__ k4 = (const float4*)(p.k + ((size_t)b<<10));
#pragma unroll
      for (int t=0;t<4;++t) kr[t] = k4[lane + 64*t];
    }
    const float c = p.q[row] * 0.03125f;
    float e[16];
#pragma unroll
    for (int t=0;t<4;++t) {
      e[4*t+0]=__expf(c*kr[t].x); e[4*t+1]=__expf(c*kr[t].y);
      e[4*t+2]=__expf(c*kr[t].z); e[4*t+3]=__expf(c*kr[t].w);
    }
    float rinv;
    if (USE_RINV) {
      rinv = p.rinv[row];
    } else {
      float sum = 0.f;
#pragma unroll
      for (int i=0;i<16;++i) sum += e[i];
#pragma unroll
      for (int off=32; off>=1; off>>=1) sum += __shfl_xor(sum, off);
      rinv = 1.f/sum;
    }
    f4n* o = (f4n*)(p.nw + ((size_t)row<<10));
#pragma unroll
    for (int t=0;t<4;++t) {
      f4n st;
      st.x=e[4*t]*rinv;   st.y=e[4*t+1]*rinv;
      st.z=e[4*t+2]*rinv; st.w=e[4*t+3]*rinv;
      __builtin_nontemporal_store(st, &o[lane + 64*t]);
    }
  }
}

// ---------------------------------------------------------------------------
// Split-K partial GEMM tile (proven): tile 128b x 64n, KC steps of 32.
// ---------------------------------------------------------------------------
__device__ __forceinline__ void gemm_tile(
    const float* __restrict__ X, const float* __restrict__ W,
    float* __restrict__ Pout, int n0, int k0, int KC,
    float* xt, float* wt)
{
  const int tid = threadIdx.x;
  const int tn = tid & 15, tb = tid >> 4;
  const int b_base = tb*8, n_base = tn*4;
  float acc[8][4];
#pragma unroll
  for (int i=0;i<8;++i)
#pragma unroll
    for (int j=0;j<4;++j) acc[i][j]=0.f;

  for (int s=0; s<KC/DS; ++s) {
    const int kk = k0 + s*DS;
#pragma unroll
    for (int r=0;r<4;++r) {
      const int row = (tid>>3) + 32*r;
      const int c0  = (tid&7)*4;
      const float4 vv = *(const float4*)(X + (size_t)row*DIM + kk + c0);
      xt[(c0+0)*132+row]=vv.x; xt[(c0+1)*132+row]=vv.y;
      xt[(c0+2)*132+row]=vv.z; xt[(c0+3)*132+row]=vv.w;
    }
#pragma unroll
    for (int r=0;r<2;++r) {
      const int row = (tid>>3) + 32*r;
      const int c0  = (tid&7)*4;
      const f4n vv = __builtin_nontemporal_load(
          (const f4n*)(W + (size_t)(n0+row)*DIM + kk + c0));
      wt[(c0+0)*68+row]=vv.x; wt[(c0+1)*68+row]=vv.y;
      wt[(c0+2)*68+row]=vv.z; wt[(c0+3)*68+row]=vv.w;
    }
    __syncthreads();
#pragma unroll 4
    for (int d=0; d<DS; ++d) {
      const float4 xa0 = *(const float4*)&xt[d*132 + b_base];
      const float4 xa1 = *(const float4*)&xt[d*132 + b_base + 4];
      const float4 wa  = *(const float4*)&wt[d*68  + n_base];
      const float xr[8] = {xa0.x,xa0.y,xa0.z,xa0.w, xa1.x,xa1.y,xa1.z,xa1.w};
      const float wr[4] = {wa.x,wa.y,wa.z,wa.w};
#pragma unroll
      for (int bb=0;bb<8;++bb)
#pragma unroll
        for (int nn=0;nn<4;++nn) acc[bb][nn] += xr[bb]*wr[nn];
    }
    __syncthreads();
  }
#pragma unroll
  for (int bb=0;bb<8;++bb) {
    const float4 st = make_float4(acc[bb][0],acc[bb][1],acc[bb][2],acc[bb][3]);
    *(float4*)(Pout + (size_t)(b_base+bb)*DIM + n0 + n_base) = st;
  }
}

__global__ __launch_bounds__(256) void qkv_partial(
    const float* __restrict__ X, const float* __restrict__ W0,
    const float* __restrict__ W1, const float* __restrict__ W2,
    float* __restrict__ P)
{
  __shared__ float xt[DS*132];
  __shared__ float wt[DS*68];
  const int z = blockIdx.z;
  const float* W = (z==0)?W0:(z==1)?W1:W2;
  gemm_tile(X, W, P + (size_t)(z*8+blockIdx.y)*MAT,
            blockIdx.x*64, blockIdx.y*128, 128, xt, wt);
}

__global__ __launch_bounds__(256) void qkv_reduce(Params p)
{
  const int t = blockIdx.x*256 + threadIdx.x;     // 0..98303
  const int z = t >> 15, idx4 = t & 32767;
  const float4* Pz = (const float4*)(p.P + (size_t)z*8*MAT);
  const float*  bias = (z==0) ? p.bq : (z==1) ? p.bk : p.bv;
  float* outz = (z==0) ? p.q : (z==1) ? p.k : p.v;
  float4 s = Pz[idx4];
#pragma unroll
  for (int sp=1; sp<8; ++sp) {
    const float4 t2 = Pz[sp*(MAT/4)+idx4];
    s.x+=t2.x; s.y+=t2.y; s.z+=t2.z; s.w+=t2.w;
  }
  const float4 b4 = ((const float4*)bias)[idx4 & 255];
  s.x+=b4.x; s.y+=b4.y; s.z+=b4.z; s.w+=b4.w;
  ((float4*)outz)[idx4] = s;
}

// ---------------------------------------------------------------------------
// attn: blocks 0..767 = AR (3072 waves x ~43 consecutive rows, k/v cached
// per batch run): araw + rinv for ALL rows, ~4.5 us. blocks 768..1023 =
// writers, 1024 waves x 5 rows = 20 MB (~matches AR duration). Balanced.
// ---------------------------------------------------------------------------
__global__ __launch_bounds__(256,4) void attn_mixed(Params p)
{
  const int bid = blockIdx.x, tid = threadIdx.x;
  const int wave = tid>>6, lane = tid&63;
  if (bid < 768) {
    const int gw = bid*4 + wave;          // 0..3071
    int r0 = gw*43, r1 = r0 + 43;
    if (r1 > NROWS) r1 = NROWS;
    if (r0 >= NROWS) return;
    int bcur = -1;
    float4 kr[4], vr[4];
#pragma unroll 1
    for (int row = r0; row < r1; ++row) {
      const int b = row >> 10;
      if (b != bcur) {
        bcur = b;
        const float4* __restrict__ k4 = (const float4*)(p.k + ((size_t)b<<10));
        const float4* __restrict__ v4 = (const float4*)(p.v + ((size_t)b<<10));
#pragma unroll
        for (int t=0;t<4;++t) { kr[t] = k4[lane + 64*t]; vr[t] = v4[lane + 64*t]; }
      }
      const float c = p.q[row] * 0.03125f;
      float sum=0.f, dot=0.f;
#pragma unroll
      for (int t=0;t<4;++t) {
        const float ex=__expf(c*kr[t].x), ey=__expf(c*kr[t].y);
        const float ez=__expf(c*kr[t].z), ew=__expf(c*kr[t].w);
        sum += (ex+ey)+(ez+ew);
        dot += ex*vr[t].x + ey*vr[t].y + ez*vr[t].z + ew*vr[t].w;
      }
#pragma unroll
      for (int off=32; off>=1; off>>=1) {
        sum += __shfl_xor(sum, off);
        dot += __shfl_xor(dot, off);
      }
      const float rinv = 1.f/sum;
      if (lane==0) { p.araw[row] = dot*rinv; p.rinv[row] = rinv; }
    }
  } else {
    const int w = (bid-768)*4 + wave;     // 0..1023
    write_chunk<false>(p, QAT_B + w*5, QAT_B + w*5 + 5, lane);
  }
}

// ---------------------------------------------------------------------------
// chainA: blocks 0..255 = split-16 GEMM partials (K=64) ~6 us;
// blocks 256..1023 = writers (3072 waves x 7 rows = 88 MB, ~19 us) — GEMM
// fully hidden. chainB: 0..127 reduce+epilogue ~2 us; 128..1023 writers
// (3584 waves x 6 = 88 MB; B3 variant: 512x6 + 3072x5 tail).
// ---------------------------------------------------------------------------
__global__ __launch_bounds__(256,4) void chainA(Params p,
    const float* __restrict__ X, const float* __restrict__ W, int wbase)
{
  __shared__ float xt[DS*132];
  __shared__ float wt[DS*68];
  const int bid = blockIdx.x, tid = threadIdx.x;
  const int wave = tid>>6, lane = tid&63;
  if (bid < 256) {
    gemm_tile(X, W, p.P + (size_t)(bid&15)*MAT, (bid>>4)*64, (bid&15)*64, 64, xt, wt);
  } else {
    const int w = (bid-256)*4 + wave;     // 0..3071
    const int r0 = wbase + w*7;
    write_chunk<true>(p, r0, r0 + 7, lane);
  }
}

__global__ __launch_bounds__(256,4) void chainB(Params p,
    const float* __restrict__ bias, const float* __restrict__ extra,
    float* __restrict__ out, int relu, int wbase, int last)
{
  const int bid = blockIdx.x, tid = threadIdx.x;
  const int wave = tid>>6, lane = tid&63;
  if (bid < 128) {
    const int idx4 = bid*256 + tid;
    const float4* P4 = (const float4*)p.P;
    float4 s = P4[idx4];
#pragma unroll
    for (int sp=1; sp<16; ++sp) {
      const float4 t2 = P4[sp*(MAT/4)+idx4];
      s.x+=t2.x; s.y+=t2.y; s.z+=t2.z; s.w+=t2.w;
    }
    const float4 b4 = ((const float4*)bias)[idx4 & 255];
    s.x+=b4.x; s.y+=b4.y; s.z+=b4.z; s.w+=b4.w;
    if (relu) { s.x=fmaxf(s.x,0.f); s.y=fmaxf(s.y,0.f);
                s.z=fmaxf(s.z,0.f); s.w=fmaxf(s.w,0.f); }
    if (extra) {
      const float4 e = ((const float4*)extra)[idx4];
      s.x+=e.x; s.y+=e.y; s.z+=e.z; s.w+=e.w;
    }
    ((float4*)out)[idx4] = s;
  } else {
    const int w = (bid-128)*4 + wave;     // 0..3583
    if (!last) {
      const int r0 = wbase + w*6;
      write_chunk<true>(p, r0, r0 + 6, lane);
    } else {
      // 18432 rows: first 512 waves x 6, remaining 3072 waves x 5
      int r0, n;
      if (w < 512) { r0 = wbase + w*6;               n = 6; }
      else         { r0 = wbase + 3072 + (w-512)*5;  n = 5; }
      write_chunk<true>(p, r0, r0 + n, lane);
    }
  }
}

// ---------------------------------------------------------------------------
extern "C" void kernel_launch(void* const* d_in, const int* in_sizes, int n_in,
                              void* d_out, int out_size, void* d_ws, size_t ws_size,
                              hipStream_t stream)
{
  (void)in_sizes; (void)n_in; (void)out_size; (void)ws_size;
  Params p;
  p.x  = (const float*)d_in[0];
  p.Wq = (const float*)d_in[1];  p.bq = (const float*)d_in[2];
  p.Wk = (const float*)d_in[3];  p.bk = (const float*)d_in[4];
  p.Wv = (const float*)d_in[5];  p.bv = (const float*)d_in[6];
  p.Wo = (const float*)d_in[7];  p.bo = (const float*)d_in[8];
  p.W1 = (const float*)d_in[9];  p.b1 = (const float*)d_in[10];
  p.W2 = (const float*)d_in[11]; p.b2 = (const float*)d_in[12];
  p.out = (float*)d_out;
  p.nw  = p.out + MAT;
  float* ws = (float*)d_ws;
  p.q    = ws;         p.k    = ws + MAT;   p.v = ws + 2*MAT;
  p.araw = ws + 3*MAT; p.x2   = ws + 4*MAT; p.h = ws + 5*MAT;
  p.rinv = ws + 6*MAT; p.P    = ws + 7*MAT;   // P: 24*MAT floats

  qkv_partial<<<dim3(16,8,3), 256, 0, stream>>>(p.x, p.Wq, p.Wk, p.Wv, p.P);
  qkv_reduce<<<384, 256, 0, stream>>>(p);

  attn_mixed<<<1024, 256, 0, stream>>>(p);

  chainA<<<1024, 256, 0, stream>>>(p, p.araw, p.Wo, A1_B);
  chainB<<<1024, 256, 0, stream>>>(p, p.bo, p.x, p.x2, 0, B1_B, 0);

  chainA<<<1024, 256, 0, stream>>>(p, p.x2, p.W1, A2_B);
  chainB<<<1024, 256, 0, stream>>>(p, p.b1, nullptr, p.h, 1, B2_B, 0);

  chainA<<<1024, 256, 0, stream>>>(p, p.h, p.W2, A3_B);
  chainB<<<1024, 256, 0, stream>>>(p, p.b2, p.x2, p.out, 0, B3_B, 1);
}